// Round 10
// baseline (787.471 us; speedup 1.0000x reference)
//
#include <hip/hip_runtime.h>
#include <math.h>

#define N_NODES   20000
#define N_EDGES   160000
#define N_LEDGES  1280000
#define N_TOTE    (N_LEDGES + N_EDGES)   // edges incl. self-loops
#define IN_FEAT   128
#define HIDDEN    64
#define FEAT      128
#define OUT_FEAT  16
#define NUM_LAYERS 8
#define ALPHA     0.1f
#define CHUNK     16

typedef __attribute__((ext_vector_type(4))) float f32x4;
typedef __attribute__((ext_vector_type(8))) short bf16x8;

__device__ __forceinline__ float2 bf2(uint u) {
  union { uint i; float f; } a, b;
  a.i = u << 16;
  b.i = u & 0xffff0000u;
  float2 r; r.x = a.f; r.y = b.f; return r;
}
__device__ __forceinline__ ushort f2bf(float f) {
  union { float f; uint i; } u; u.f = f;
  uint r = u.i + 0x7fffu + ((u.i >> 16) & 1u);
  return (ushort)(r >> 16);
}
__device__ __forceinline__ uint pack2(float x, float y) {
  return (uint)f2bf(x) | ((uint)f2bf(y) << 16);
}

// ====== K1: cnt-count(+rank) | deg-count | lin0 | prepw | prepw1 ======
// [0,1250): cnt histogram over lrow + rank ; [1250,2500): deg histogram over lcol
// [2500,7500): lin0+relu ; [7500,8012): prepw ; [8012,8020): prepw1
__global__ __launch_bounds__(256) void k_pre(const int4* __restrict__ lrow4,
                                             const int4* __restrict__ lcol4,
                                             int* __restrict__ cnt,
                                             int* __restrict__ deg,
                                             int4* __restrict__ rank4,
                                             const float* __restrict__ x,
                                             const float* __restrict__ w0,
                                             const float* __restrict__ b0,
                                             float* __restrict__ h,
                                             const float* __restrict__ W,
                                             ushort* __restrict__ Bt,
                                             const float* __restrict__ W1,
                                             ushort* __restrict__ W1f) {
  int bid = blockIdx.x;
  int tid = threadIdx.x;
  if (bid < 1250) {
    int k4 = bid * 256 + tid;           // < 320000 exactly
    int4 r = lrow4[k4];
    int4 rk;
    rk.x = atomicAdd(&cnt[r.x], 1);
    rk.y = atomicAdd(&cnt[r.y], 1);
    rk.z = atomicAdd(&cnt[r.z], 1);
    rk.w = atomicAdd(&cnt[r.w], 1);
    rank4[k4] = rk;
  } else if (bid < 2500) {
    int k4 = (bid - 1250) * 256 + tid;  // < 320000 exactly
    int4 c = lcol4[k4];
    atomicAdd(&deg[c.x], 1); atomicAdd(&deg[c.y], 1);
    atomicAdd(&deg[c.z], 1); atomicAdd(&deg[c.w], 1);
  } else if (bid < 7500) {
    int node = (bid - 2500) * 4 + (tid >> 6);
    int j = tid & 63;
    const float* xr = x + (size_t)node * IN_FEAT;
    float acc = b0[j];
    #pragma unroll
    for (int k = 0; k < IN_FEAT; k++) acc = fmaf(xr[k], w0[k * HIDDEN + j], acc);
    h[(size_t)node * HIDDEN + j] = fmaxf(acc, 0.f);
  } else if (bid < 8012) {
    // Bt[l][c][k] = bf16(beta*W[l][k][c] + (k==c)*(1-beta))
    int gid = (bid - 7500) * 256 + tid;  // < 131072 exactly
    int l = gid >> 14;
    int rem = gid & 16383;
    int k = rem >> 7, c = rem & 127;
    float beta = logf(0.5f / (float)(l + 1) + 1.0f);
    float v = beta * W[gid];
    if (k == c) v += 1.0f - beta;
    Bt[(l << 14) + (c << 7) + k] = f2bf(v);
  } else {
    int gid = (bid - 8012) * 256 + tid;
    if (gid < FEAT * OUT_FEAT) {
      int k = gid >> 4, c = gid & 15;
      W1f[c * FEAT + k] = f2bf(W1[gid]);
    }
  }
}

// ====== K2: build_e(->x0 only) | scanA ======
// [0,20000): x0[i]=[h[src]||h[dst]] ; [20000,20157): scanA (row len = cnt+1)
__global__ __launch_bounds__(256) void k_mid(const int* __restrict__ src,
                                             const int* __restrict__ dst,
                                             const float* __restrict__ h,
                                             ushort* __restrict__ x0,
                                             const int* __restrict__ cnt,
                                             int* __restrict__ rp_out,
                                             int* __restrict__ bsum) {
  int bid = blockIdx.x;
  int tid = threadIdx.x;
  if (bid < 20000) {
    int gid = bid * 256 + tid;
    int edge = gid >> 5;
    int p = gid & 31;
    int n = (p < 16) ? src[edge] : dst[edge];
    float4 v = ((const float4*)(h + (size_t)n * HIDDEN))[p & 15];
    uint2 pk;
    pk.x = pack2(v.x, v.y);
    pk.y = pack2(v.z, v.w);
    ((uint2*)(x0 + ((size_t)edge << 7)))[p] = pk;
  } else {
    // scanA over (cnt+1)
    __shared__ int sh[256];
    int sb = bid - 20000;
    int base = sb * 1024 + tid * 4;
    int v[4];
    #pragma unroll
    for (int i = 0; i < 4; i++) v[i] = (base + i < N_EDGES) ? cnt[base + i] + 1 : 0;
    int t = v[0] + v[1] + v[2] + v[3];
    sh[tid] = t;
    __syncthreads();
    for (int off = 1; off < 256; off <<= 1) {
      int xv = (tid >= off) ? sh[tid - off] : 0;
      __syncthreads();
      sh[tid] += xv;
      __syncthreads();
    }
    int run = sh[tid] - t;
    #pragma unroll
    for (int i = 0; i < 4; i++) {
      if (base + i < N_EDGES) rp_out[base + i] = run;
      run += v[i];
    }
    if (tid == 255) bsum[sb] = sh[255];
  }
}

__global__ void k_scanB(int* __restrict__ bsum, int nb) {
  __shared__ int sh[256];
  int tid = threadIdx.x;
  int v = (tid < nb) ? bsum[tid] : 0;
  sh[tid] = v;
  __syncthreads();
  for (int off = 1; off < 256; off <<= 1) {
    int xv = (tid >= off) ? sh[tid - off] : 0;
    __syncthreads();
    sh[tid] += xv;
    __syncthreads();
  }
  if (tid < nb) bsum[tid] = sh[tid] - v;  // exclusive
}

// ====== K4: scanC | dis ======
__global__ __launch_bounds__(256) void k_scanC(int* __restrict__ row_ptr,
                                               const int* __restrict__ bsum,
                                               const int* __restrict__ deg,
                                               float* __restrict__ dis) {
  int bid = blockIdx.x;
  int tid = threadIdx.x;
  if (bid < 157) {
    int base = bid * 1024 + tid * 4;
    int add = bsum[bid];
    #pragma unroll
    for (int i = 0; i < 4; i++)
      if (base + i < N_EDGES) row_ptr[base + i] += add;
    if (bid == 0 && tid == 0) row_ptr[N_EDGES] = N_TOTE;
  } else {
    int i = (bid - 157) * 256 + tid;
    if (i < N_EDGES) dis[i] = rsqrtf((float)(deg[i] + 1));  // +1 self-loop
  }
}

// ====== K5: fill (NO atomics; uses rank) ======
__global__ __launch_bounds__(256) void k_fill(const int* __restrict__ lrow,
                                              const int* __restrict__ lcol,
                                              const int* __restrict__ rank,
                                              const int* __restrict__ row_ptr,
                                              const float* __restrict__ dis,
                                              uint2* __restrict__ pv) {
  int bid = blockIdx.x;
  int tid = threadIdx.x;
  if (bid < 5000) {
    int k = bid * 256 + tid;             // < 1280000 exactly
    int r = lrow[k], c = lcol[k];
    int pos = row_ptr[r] + rank[k];
    uint2 out;
    out.x = (uint)c;
    out.y = __float_as_uint((1.f - ALPHA) * dis[r] * dis[c]);
    pv[pos] = out;
  } else {
    int r = (bid - 5000) * 256 + tid;    // < 160000 exactly
    int pos = row_ptr[r + 1] - 1;
    float d = dis[r];
    uint2 out;
    out.x = (uint)r;
    out.y = __float_as_uint((1.f - ALPHA) * d * d);
    pv[pos] = out;
  }
}

// ---------------- gather phase: segmented stream, 16 gathers in flight ----
// One 16-entry pv line per chunk; entry broadcast via v_readlane (SALU);
// gather base in SGPR; alpha*x0 folded at flush (x0 row prefetched).
__device__ __forceinline__ void gather_phase(const int* __restrict__ row_ptr,
                                             const uint2* __restrict__ pv,
                                             const uint* __restrict__ eu,
                                             const uint* __restrict__ x0u,
                                             ushort* As, int row0, int wv, int lane) {
  int r0w = row0 + wv * 16;
  int rpidx = r0w + lane;
  if (rpidx > N_EDGES) rpidx = N_EDGES;
  int myrp = row_ptr[rpidx];

  int t    = __builtin_amdgcn_readlane(myrp, 0);
  int tend = __builtin_amdgcn_readlane(myrp, 16);
  int r    = r0w;
  int end  = __builtin_amdgcn_readlane(myrp, 1);

  float ax = 0.f, ay = 0.f;
  uint uA[CHUNK], uB[CHUNK];
  uint2 P, Pn;
  uint xq = x0u[((size_t)r0w << 6) + lane];   // x0 row prefetch

  auto loadpv16 = [&](int tb_, uint2& p) {
    p = pv[tb_ + (lane & 15)];            // 128B line = one 16-edge chunk
  };
  auto gather16 = [&](int tb_, const uint2& p, uint* uu) {
    #pragma unroll
    for (int j = 0; j < CHUNK; j++) {
      int cu = (tb_ + j < tend)
                 ? __builtin_amdgcn_readlane((int)p.x, j)
                 : 0;
      uu[j] = eu[((size_t)cu << 6) + lane];
    }
  };
  auto flush = [&]() {
    int rl = r - row0;
    float2 fx = bf2(xq);
    *(uint*)((char*)As + rl * 256 + ((lane * 4) ^ ((rl & 7) << 4))) =
        pack2(fmaf(ALPHA, fx.x, ax), fmaf(ALPHA, fx.y, ay));
    ax = 0.f; ay = 0.f;
    if (r + 1 < r0w + 16) xq = x0u[((size_t)(r + 1) << 6) + lane];  // next row
  };
  auto consume16 = [&](int tb_, const uint2& p, const uint* uu) {
    #pragma unroll
    for (int j = 0; j < CHUNK; j++) {
      int tj = tb_ + j;
      if (tj < tend) {                      // wave-uniform
        while (tj >= end) {                 // row boundary (wave-uniform)
          flush();
          r++;
          end = __builtin_amdgcn_readlane(myrp, r - r0w + 1);
        }
        float v = __uint_as_float(__builtin_amdgcn_readlane((int)p.y, j));
        float2 f = bf2(uu[j]);
        ax = fmaf(v, f.x, ax);
        ay = fmaf(v, f.y, ay);
      }
    }
  };

  int tb = t;
  loadpv16(tb, P);
  gather16(tb, P, uA);
  while (true) {
    if (tb + CHUNK < tend) { loadpv16(tb + CHUNK, Pn); gather16(tb + CHUNK, Pn, uB); }
    consume16(tb, P, uA);
    tb += CHUNK;
    if (tb >= tend) break;
    if (tb + CHUNK < tend) { loadpv16(tb + CHUNK, P); gather16(tb + CHUNK, P, uA); }
    consume16(tb, Pn, uB);
    tb += CHUNK;
    if (tb >= tend) break;
  }
  flush();  // last row (every row has >=1 edge via self-loop)
}

// ---------------- MFMA accumulate: acc = As@W' ----------------
__device__ __forceinline__ void mfma_accum(const ushort* As,
                                           const ushort* __restrict__ Bt,
                                           int wv, int l15, int l4,
                                           f32x4 acc[4][2]) {
  const char* btA = (const char*)Bt + (size_t)(wv * 32 + l15) * 256;
  const char* btB = btA + 16 * 256;
  #pragma unroll
  for (int kb = 0; kb < 4; kb++) {
    int kbyte = kb * 64 + l4 * 16;
    bf16x8 b0 = *(const bf16x8*)(btA + kbyte);
    bf16x8 b1 = *(const bf16x8*)(btB + kbyte);
    #pragma unroll
    for (int mr = 0; mr < 4; mr++) {
      int rr = mr * 16 + l15;
      bf16x8 afr = *(const bf16x8*)((const char*)As + rr * 256 + (kbyte ^ ((rr & 7) << 4)));
      acc[mr][0] = __builtin_amdgcn_mfma_f32_16x16x32_bf16(afr, b0, acc[mr][0], 0, 0, 0);
      acc[mr][1] = __builtin_amdgcn_mfma_f32_16x16x32_bf16(afr, b1, acc[mr][1], 0, 0, 0);
    }
  }
}

// ---------------- fused layer (layers 0..6): -> e_out bf16 ----------------
__global__ __launch_bounds__(256, 6) void k_layer(const int* __restrict__ row_ptr,
                                                  const uint2* __restrict__ pv,
                                                  const ushort* __restrict__ e_in,
                                                  const ushort* __restrict__ x0,
                                                  const ushort* __restrict__ Bt,
                                                  ushort* __restrict__ e_out) {
  __shared__ __align__(16) ushort As[64 * 128];  // 16KB
  int tid = threadIdx.x;
  int wv = tid >> 6, lane = tid & 63;
  int l15 = lane & 15, l4 = lane >> 4;
  int row0 = blockIdx.x * 64;

  gather_phase(row_ptr, pv, (const uint*)e_in, (const uint*)x0, As, row0, wv, lane);
  __syncthreads();

  f32x4 acc[4][2];
  #pragma unroll
  for (int i = 0; i < 4; i++) { acc[i][0] = (f32x4)0; acc[i][1] = (f32x4)0; }
  mfma_accum(As, Bt, wv, l15, l4, acc);

  __syncthreads();  // all waves done reading As
  // stage relu(acc) into As as [row][col] bf16 (XOR bits 4-6 per row)
  #pragma unroll
  for (int mr = 0; mr < 4; mr++) {
    #pragma unroll
    for (int n = 0; n < 2; n++) {
      int col = wv * 32 + n * 16 + l15;
      #pragma unroll
      for (int j = 0; j < 4; j++) {
        int rl = mr * 16 + l4 * 4 + j;
        float v = fmaxf(acc[mr][n][j], 0.f);
        *(ushort*)((char*)As + rl * 256 + ((col * 2) ^ ((rl & 7) << 4))) = f2bf(v);
      }
    }
  }
  __syncthreads();
  // full-line coalesced copy-out: 1024 16B chunks
  const char* asb = (const char*)As;
  #pragma unroll
  for (int k2 = 0; k2 < 4; k2++) {
    int q = k2 * 256 + tid;
    int rl = q >> 4, ck = q & 15;
    uint4 v = *(const uint4*)(asb + rl * 256 + ((ck * 16) ^ ((rl & 7) << 4)));
    *(uint4*)((char*)e_out + (((size_t)(row0 + rl)) << 8) + ck * 16) = v;
  }
}

// ---------------- last layer: fused lin1, writes out fp32 ----------------
__global__ __launch_bounds__(256, 4) void k_layer_last(const int* __restrict__ row_ptr,
                                                       const uint2* __restrict__ pv,
                                                       const ushort* __restrict__ e_in,
                                                       const ushort* __restrict__ x0,
                                                       const ushort* __restrict__ Bt,
                                                       const ushort* __restrict__ W1f,
                                                       const float* __restrict__ b1,
                                                       float* __restrict__ out) {
  __shared__ __align__(16) ushort As[64 * 128];  // 16KB
  int tid = threadIdx.x;
  int wv = tid >> 6, lane = tid & 63;
  int l15 = lane & 15, l4 = lane >> 4;
  int row0 = blockIdx.x * 64;

  gather_phase(row_ptr, pv, (const uint*)e_in, (const uint*)x0, As, row0, wv, lane);
  __syncthreads();

  f32x4 acc[4][2];
  #pragma unroll
  for (int i = 0; i < 4; i++) { acc[i][0] = (f32x4)0; acc[i][1] = (f32x4)0; }
  mfma_accum(As, Bt, wv, l15, l4, acc);

  __syncthreads();  // all waves done reading As
  // relu -> bf16 e-tile back into As (swizzled)
  #pragma unroll
  for (int mr = 0; mr < 4; mr++) {
    #pragma unroll
    for (int n = 0; n < 2; n++) {
      int col = wv * 32 + n * 16 + l15;
      #pragma unroll
      for (int j = 0; j < 4; j++) {
        int rl = mr * 16 + l4 * 4 + j;
        float v = fmaxf(acc[mr][n][j], 0.f);
        *(ushort*)((char*)As + rl * 256 + ((col * 2) ^ ((rl & 7) << 4))) = f2bf(v);
      }
    }
  }
  __syncthreads();

  // lin1: out(64x16) = e_tile(64x128) @ W1(128x16) + b1
  f32x4 acc2[4];
  #pragma unroll
  for (int i = 0; i < 4; i++) acc2[i] = (f32x4)0;
  const char* w1p = (const char*)W1f + (size_t)l15 * 256;
  #pragma unroll
  for (int kb = 0; kb < 4; kb++) {
    int kbyte = kb * 64 + l4 * 16;
    bf16x8 wfr = *(const bf16x8*)(w1p + kbyte);
    #pragma unroll
    for (int mr = 0; mr < 4; mr++) {
      int rr = mr * 16 + l15;
      bf16x8 afr = *(const bf16x8*)((const char*)As + rr * 256 + (kbyte ^ ((rr & 7) << 4)));
      acc2[mr] = __builtin_amdgcn_mfma_f32_16x16x32_bf16(afr, wfr, acc2[mr], 0, 0, 0);
    }
  }
  float bias = b1[l15];
  #pragma unroll
  for (int mr = 0; mr < 4; mr++) {
    int rowb = row0 + mr * 16 + l4 * 4;
    #pragma unroll
    for (int j = 0; j < 4; j++)
      out[(size_t)(rowb + j) * OUT_FEAT + l15] = acc2[mr][j] + bias;
  }
}

extern "C" void kernel_launch(void* const* d_in, const int* in_sizes, int n_in,
                              void* d_out, int out_size, void* d_ws, size_t ws_size,
                              hipStream_t stream) {
  const float* x   = (const float*)d_in[0];
  const int*   ei  = (const int*)d_in[1];
  const int*   lei = (const int*)d_in[2];
  const float* w0  = (const float*)d_in[3];
  const float* b0  = (const float*)d_in[4];
  const float* cw  = (const float*)d_in[5];
  const float* w1  = (const float*)d_in[6];
  const float* b1  = (const float*)d_in[7];
  float* out = (float*)d_out;

  char* ws = (char*)d_ws;
  size_t off = 0;
  auto alloc = [&](size_t bytes) -> void* {
    void* p = ws + off;
    off += (bytes + 255) & ~(size_t)255;
    return p;
  };
  float*  h      = (float*)alloc((size_t)N_NODES * HIDDEN * 4);
  ushort* x0m    = (ushort*)alloc((size_t)N_EDGES * FEAT * 2);
  ushort* eB     = (ushort*)alloc((size_t)N_EDGES * FEAT * 2);
  ushort* eC     = (ushort*)alloc((size_t)N_EDGES * FEAT * 2);
  ushort* Btp    = (ushort*)alloc((size_t)NUM_LAYERS * FEAT * FEAT * 2);
  ushort* W1f    = (ushort*)alloc((size_t)FEAT * OUT_FEAT * 2);
  int*    deg    = (int*)alloc((size_t)N_EDGES * 4);
  float*  dis    = (float*)alloc((size_t)N_EDGES * 4);
  int*    cnt    = (int*)alloc((size_t)N_EDGES * 4);
  int*    rank   = (int*)alloc((size_t)N_LEDGES * 4);
  int*    row_ptr= (int*)alloc((size_t)(N_EDGES + 1) * 4);
  uint2*  pv     = (uint2*)alloc(((size_t)N_TOTE + 64) * 8);  // +pad for unguarded loads
  int*    bsum   = (int*)alloc(256 * 4);

  hipMemsetAsync(cnt, 0, (size_t)N_EDGES * 4, stream);
  hipMemsetAsync(deg, 0, (size_t)N_EDGES * 4, stream);

  // K1: cnt-count(+rank) | deg-count | lin0 | prepw | prepw1
  k_pre<<<8020, 256, 0, stream>>>((const int4*)lei, (const int4*)(lei + N_LEDGES),
                                  cnt, deg, (int4*)rank,
                                  x, w0, b0, h, cw, Btp, w1, W1f);
  // K2: build_e(->x0) | scanA
  k_mid<<<20157, 256, 0, stream>>>(ei, ei + N_EDGES, h, x0m, cnt, row_ptr, bsum);
  k_scanB<<<1, 256, 0, stream>>>(bsum, 157);
  // K4: scanC | dis
  k_scanC<<<782, 256, 0, stream>>>(row_ptr, bsum, deg, dis);
  // K5: fill, no atomics
  k_fill<<<5625, 256, 0, stream>>>(lei, lei + N_LEDGES, rank, row_ptr, dis, pv);

  ushort* bufs[2] = { eB, eC };
  ushort* ein = x0m;
  for (int l = 0; l < NUM_LAYERS - 1; l++) {
    k_layer<<<N_EDGES / 64, 256, 0, stream>>>(row_ptr, pv, ein, x0m,
                                              Btp + ((size_t)l << 14), bufs[l & 1]);
    ein = bufs[l & 1];
  }
  k_layer_last<<<N_EDGES / 64, 256, 0, stream>>>(row_ptr, pv, ein, x0m,
                                                 Btp + ((size_t)(NUM_LAYERS - 1) << 14),
                                                 W1f, b1, out);
}